// Round 1
// baseline (434.825 us; speedup 1.0000x reference)
//
#include <hip/hip_runtime.h>

// LIF neuron forward: x [B=16, C=64, T=16, H=64, W=64] f32, decay (1,) f32.
// Recurrence over T (stride H*W in memory within each (b,c) block):
//   mem   = mem_old * sigmoid(decay) * (1 - spike) + x_t
//   spike = (mem > 0.5) ? 1 : 0
// Output = spikes (clip(0,1) is a no-op on {0,1}).
//
// Layout: for fixed (b,c) the [T, H, W] block is contiguous; element (t, s)
// (s = h*W+w in [0, 4096)) sits at ((b*C+c)*T + t)*HW + s.
// One thread owns one (bc, s4) column: 4 consecutive w values across all 16
// timesteps -> 16 coalesced float4 loads + 16 coalesced float4 stores.

#define T_STEPS 16
#define HW      4096            // H*W = 64*64
#define BC      1024            // B*C = 16*64
#define S4      1024            // HW / 4 float4-columns per (b,c)

__global__ __launch_bounds__(256) void
lif_fwd_kernel(const float* __restrict__ x,
               const float* __restrict__ decay,
               float* __restrict__ out) {
    const int tid = blockIdx.x * blockDim.x + threadIdx.x;   // [0, BC*S4)
    const int bc  = tid >> 10;                               // / S4
    const int s4  = tid & (S4 - 1);
    const long base = (long)bc * (T_STEPS * HW) + (long)s4 * 4;

    // sigmoid(decay) — match reference fp32 semantics (no fast-math expf).
    const float d  = decay[0];
    const float ds = 1.0f / (1.0f + expf(-d));

    float mem_x = 0.f, mem_y = 0.f, mem_z = 0.f, mem_w = 0.f;
    float sp_x  = 0.f, sp_y  = 0.f, sp_z  = 0.f, sp_w  = 0.f;

#pragma unroll
    for (int t = 0; t < T_STEPS; ++t) {
        const long off = base + (long)t * HW;
        const float4 xv = *reinterpret_cast<const float4*>(x + off);

        // Un-fused fp32 ops to mirror XLA's separate mul/mul/add rounding.
        mem_x = __fadd_rn(__fmul_rn(__fmul_rn(mem_x, ds), 1.0f - sp_x), xv.x);
        mem_y = __fadd_rn(__fmul_rn(__fmul_rn(mem_y, ds), 1.0f - sp_y), xv.y);
        mem_z = __fadd_rn(__fmul_rn(__fmul_rn(mem_z, ds), 1.0f - sp_z), xv.z);
        mem_w = __fadd_rn(__fmul_rn(__fmul_rn(mem_w, ds), 1.0f - sp_w), xv.w);

        sp_x = (mem_x > 0.5f) ? 1.0f : 0.0f;
        sp_y = (mem_y > 0.5f) ? 1.0f : 0.0f;
        sp_z = (mem_z > 0.5f) ? 1.0f : 0.0f;
        sp_w = (mem_w > 0.5f) ? 1.0f : 0.0f;

        float4 ov;
        ov.x = sp_x; ov.y = sp_y; ov.z = sp_z; ov.w = sp_w;
        *reinterpret_cast<float4*>(out + off) = ov;
    }
}

extern "C" void kernel_launch(void* const* d_in, const int* in_sizes, int n_in,
                              void* d_out, int out_size, void* d_ws, size_t ws_size,
                              hipStream_t stream) {
    const float* x     = (const float*)d_in[0];
    const float* decay = (const float*)d_in[1];
    float*       out   = (float*)d_out;

    const int total_threads = BC * S4;               // 1,048,576
    const int block = 256;
    const int grid  = total_threads / block;         // 4096

    lif_fwd_kernel<<<grid, block, 0, stream>>>(x, decay, out);
}

// Round 2
// 427.969 us; speedup vs baseline: 1.0160x; 1.0160x over previous
//
#include <hip/hip_runtime.h>

// LIF neuron forward: x [B=16, C=64, T=16, H=64, W=64] f32, decay (1,) f32.
//   mem   = mem_old * sigmoid(decay) * (1 - spike) + x_t
//   spike = (mem > 0.5) ? 1 : 0
// out = spikes (clip(0,1) is identity on {0,1}).
//
// Round 1 changes vs round 0:
//  - Phase 1 issues ALL 16 strided float4 loads up front (16 outstanding
//    VMEM ops/wave) before the dependent recurrence consumes them. Round-0
//    interleaved load/compute/store likely serialized on vmcnt.
//  - Nontemporal load/store: both streams are touch-once; keep them out of
//    L2/LLC so read and write streams don't evict each other.
//  - 32-bit element offsets (array is 268 MB < 4 GB).

#define T_STEPS 16
#define HW      4096            // H*W
#define BC      1024            // B*C
#define S4      1024            // HW/4 float4 columns per (b,c)

typedef float f4 __attribute__((ext_vector_type(4)));

__global__ __launch_bounds__(256) void
lif_fwd_kernel(const float* __restrict__ x,
               const float* __restrict__ decay,
               float* __restrict__ out) {
    const unsigned tid = blockIdx.x * blockDim.x + threadIdx.x;  // [0, BC*S4)
    const unsigned bc  = tid >> 10;
    const unsigned s4  = tid & (S4 - 1);
    const unsigned base = bc * (T_STEPS * HW) + s4 * 4;          // element offset

    const float d  = decay[0];
    const float ds = 1.0f / (1.0f + expf(-d));

    // Phase 1: all loads in flight.
    f4 xv[T_STEPS];
#pragma unroll
    for (int t = 0; t < T_STEPS; ++t) {
        xv[t] = __builtin_nontemporal_load(
            reinterpret_cast<const f4*>(x + base + (unsigned)t * HW));
    }

    // Phase 2: sequential recurrence, store per step.
    float mx = 0.f, my = 0.f, mz = 0.f, mw = 0.f;
    float sx = 0.f, sy = 0.f, sz = 0.f, sw = 0.f;
#pragma unroll
    for (int t = 0; t < T_STEPS; ++t) {
        mx = __fadd_rn(__fmul_rn(__fmul_rn(mx, ds), 1.0f - sx), xv[t].x);
        my = __fadd_rn(__fmul_rn(__fmul_rn(my, ds), 1.0f - sy), xv[t].y);
        mz = __fadd_rn(__fmul_rn(__fmul_rn(mz, ds), 1.0f - sz), xv[t].z);
        mw = __fadd_rn(__fmul_rn(__fmul_rn(mw, ds), 1.0f - sw), xv[t].w);

        sx = (mx > 0.5f) ? 1.0f : 0.0f;
        sy = (my > 0.5f) ? 1.0f : 0.0f;
        sz = (mz > 0.5f) ? 1.0f : 0.0f;
        sw = (mw > 0.5f) ? 1.0f : 0.0f;

        f4 ov;
        ov.x = sx; ov.y = sy; ov.z = sz; ov.w = sw;
        __builtin_nontemporal_store(ov,
            reinterpret_cast<f4*>(out + base + (unsigned)t * HW));
    }
}

extern "C" void kernel_launch(void* const* d_in, const int* in_sizes, int n_in,
                              void* d_out, int out_size, void* d_ws, size_t ws_size,
                              hipStream_t stream) {
    const float* x     = (const float*)d_in[0];
    const float* decay = (const float*)d_in[1];
    float*       out   = (float*)d_out;

    const int block = 256;
    const int grid  = (BC * S4) / block;   // 4096 blocks
    lif_fwd_kernel<<<grid, block, 0, stream>>>(x, decay, out);
}